// Round 2
// baseline (393.481 us; speedup 1.0000x reference)
//
#include <hip/hip_runtime.h>
#include <hip/hip_bf16.h>

// B=8, LQ=LK=2048, D=128, fp32 in/out, softmax(qk*scale) @ V.
// S^T/O^T orientation flash attention: q in lane dim, kk in reg dim.
// No shared-LDS staging, no barriers; K/V A-frags direct from L2.
// bf16x3 split QK^T for fp32-accurate logits; bf16 PV; ksplit=4 + merge.

typedef float          f32x4 __attribute__((ext_vector_type(4)));
typedef short          s16x8 __attribute__((ext_vector_type(8)));
typedef unsigned int   u32x4 __attribute__((ext_vector_type(4)));
typedef unsigned short u16x4 __attribute__((ext_vector_type(4)));

#define LOG2E 1.4426950408889634f

__device__ __forceinline__ float fast_exp2(float x) {
#if __has_builtin(__builtin_amdgcn_exp2f)
    return __builtin_amdgcn_exp2f(x);
#else
    return exp2f(x);
#endif
}
__device__ __forceinline__ unsigned short f2bf(float x) {
    return __builtin_bit_cast(unsigned short, __float2bfloat16(x));
}
__device__ __forceinline__ float bf2f(unsigned short u) {
    return __bfloat162float(__builtin_bit_cast(__hip_bfloat16, u));
}

// ---------------- fp32 -> bf16 hi/lo split, Q and K fused ----------------
__global__ void conv_split2(const float* __restrict__ q, const float* __restrict__ k,
                            unsigned short* __restrict__ qh, unsigned short* __restrict__ ql,
                            unsigned short* __restrict__ kh, unsigned short* __restrict__ kl) {
    const int bid  = blockIdx.x;
    const int half = bid >> 11;                       // 0: q, 1: k
    const int i    = (bid & 2047) * 256 + threadIdx.x; // float4 idx, 524288 per half
    const float* src = half ? k : q;
    unsigned short* hi = half ? kh : qh;
    unsigned short* lo = half ? kl : ql;
    const float4 v = ((const float4*)src)[i];
    float f[4] = {v.x, v.y, v.z, v.w};
    u16x4 h, l;
#pragma unroll
    for (int j = 0; j < 4; ++j) {
        unsigned short hb = f2bf(f[j]);
        h[j] = hb;
        l[j] = f2bf(f[j] - bf2f(hb));
    }
    ((u16x4*)hi)[i] = h;
    ((u16x4*)lo)[i] = l;
}

// -------- V [b][k][d] fp32 -> V^T [b][d][2048] bf16 (1024 blocks) --------
__global__ void transpose_v(const float* __restrict__ v,
                            unsigned short* __restrict__ vt) {
    __shared__ unsigned short tile[64 * 36];          // [k 64][d_local 32 +4 pad]
    const int b    = blockIdx.x & 7;
    const int rest = blockIdx.x >> 3;                 // 0..127
    const int k0   = (rest & 31) * 64;
    const int d0   = (rest >> 5) * 32;
    const int tid  = threadIdx.x;
#pragma unroll
    for (int it = 0; it < 2; ++it) {
        int idx = it * 256 + tid;                     // 0..511
        int kk  = idx >> 3;                           // 0..63
        int d4  = idx & 7;                            // d_local = d4*4
        float4 val = ((const float4*)v)[((b * 2048 + k0 + kk) * 128 + d0 + d4 * 4) >> 2];
        u16x4 t4;
        t4[0] = f2bf(val.x); t4[1] = f2bf(val.y);
        t4[2] = f2bf(val.z); t4[3] = f2bf(val.w);
        *(u16x4*)&tile[kk * 36 + d4 * 4] = t4;
    }
    __syncthreads();
    {
        int d  = tid >> 3;                            // 0..31
        int k8 = tid & 7;                             // 0..7
        u16x4 a, cgrp;
#pragma unroll
        for (int j = 0; j < 4; ++j) a[j]    = tile[(k8 * 8 + j) * 36 + d];
#pragma unroll
        for (int j = 0; j < 4; ++j) cgrp[j] = tile[(k8 * 8 + 4 + j) * 36 + d];
        unsigned short* outp = vt + (b * 128 + d0 + d) * 2048 + k0 + k8 * 8;
        *(u16x4*)outp       = a;
        *(u16x4*)(outp + 4) = cgrp;
    }
}

// ---------------- flash attention main kernel (S^T orientation) ----------------
#define KSPLIT 4
#define NKC    8          // kc chunks of 64 keys each (512 per split)

__global__ __launch_bounds__(256, 4)
void flash_fwd(const unsigned short* __restrict__ qh_g,
               const unsigned short* __restrict__ ql_g,
               const unsigned short* __restrict__ kh_g,
               const unsigned short* __restrict__ kl_g,
               const unsigned short* __restrict__ vt_g,
               const float* __restrict__ scale_g,
               unsigned short* __restrict__ opart,
               float* __restrict__ mpart,
               float* __restrict__ lpart) {
    // per-wave private P^T buffer [q=16][kk=64 +8 pad], XOR-swizzled
    __shared__ unsigned short lds_p[4][16 * 72];

    const int tid  = threadIdx.x;
    const int wave = tid >> 6;
    const int lane = tid & 63;
    const int c    = lane & 15;       // q (lane dim of S^T / O^T)
    const int g    = lane >> 4;       // quad
    const int xr   = (c & 3) << 3;    // P^T kk XOR swizzle

    const int bid = blockIdx.x;
    const int b   = bid & 7;          // batch <-> XCD affinity
    const int qt  = (bid >> 3) & 31;
    const int ks  = bid >> 8;         // 0..3
    const int q0  = qt * 64;
    const int kbase = ks * 512;

    const int qrow = b * 2048 + q0 + wave * 16 + c;

    // Q B-fragments: b[n=q=c][k=dd=32*kstep+8g+j]
    s16x8 qhB[4], qlB[4];
#pragma unroll
    for (int kstep = 0; kstep < 4; ++kstep) {
        int idx = qrow * 16 + kstep * 4 + g;
        qhB[kstep] = __builtin_bit_cast(s16x8, ((const u32x4*)qh_g)[idx]);
        qlB[kstep] = __builtin_bit_cast(s16x8, ((const u32x4*)ql_g)[idx]);
    }

    f32x4 oacc[8];
#pragma unroll
    for (int t = 0; t < 8; ++t) oacc[t] = (f32x4){0.f, 0.f, 0.f, 0.f};
    float m2 = -INFINITY, ln = 0.f;
    unsigned short* pw = &lds_p[wave][0];

    for (int kc = 0; kc < NKC; ++kc) {
        const int k0 = kbase + kc * 64;

        // scale: lane (c,g) needs sc[q=c][kk=16t+4g+r] -> 4 float4 loads
        f32x4 scf[4];
        {
            const int sidx = qrow * 512 + (k0 >> 2) + g;
#pragma unroll
            for (int t = 0; t < 4; ++t)
                scf[t] = ((const f32x4*)scale_g)[sidx + 4 * t];
        }

        // ---- S^T = K Q^T, bf16x3, depth-1 pipelined K-frag loads ----
        f32x4 st[4];
#pragma unroll
        for (int t = 0; t < 4; ++t) st[t] = (f32x4){0.f, 0.f, 0.f, 0.f};
        {
            const u32x4* khp = (const u32x4*)kh_g + ((b * 2048 + k0 + c) * 16 + g);
            const u32x4* klp = (const u32x4*)kl_g + ((b * 2048 + k0 + c) * 16 + g);
            // pair p: t = p&3 (kk tile), kstep = p>>2 ; offset = t*256 + kstep*4
            s16x8 khf = __builtin_bit_cast(s16x8, khp[0]);
            s16x8 klf = __builtin_bit_cast(s16x8, klp[0]);
#pragma unroll
            for (int p = 0; p < 16; ++p) {
                const int t = p & 3, kstep = p >> 2;
                s16x8 khn, kln;
                if (p < 15) {
                    const int off = ((p + 1) & 3) * 256 + ((p + 1) >> 2) * 4;
                    khn = __builtin_bit_cast(s16x8, khp[off]);
                    kln = __builtin_bit_cast(s16x8, klp[off]);
                }
                st[t] = __builtin_amdgcn_mfma_f32_16x16x32_bf16(khf, qhB[kstep], st[t], 0, 0, 0);
                st[t] = __builtin_amdgcn_mfma_f32_16x16x32_bf16(klf, qhB[kstep], st[t], 0, 0, 0);
                st[t] = __builtin_amdgcn_mfma_f32_16x16x32_bf16(khf, qlB[kstep], st[t], 0, 0, 0);
                if (p < 15) { khf = khn; klf = kln; }
            }
        }

        // ---- online softmax: row q=c spans only the 4 g-lanes ----
        float lt[4][4];
        float mx = -INFINITY;
#pragma unroll
        for (int t = 0; t < 4; ++t)
#pragma unroll
            for (int r = 0; r < 4; ++r) {
                lt[t][r] = st[t][r] * (scf[t][r] * LOG2E);
                mx = fmaxf(mx, lt[t][r]);
            }
        mx = fmaxf(mx, __shfl_xor(mx, 16));
        mx = fmaxf(mx, __shfl_xor(mx, 32));
        const float mn = fmaxf(m2, mx);
        const float al = fast_exp2(m2 - mn);   // first iter: exp2(-inf)=0
        m2 = mn;
        float rs = 0.f;
#pragma unroll
        for (int t = 0; t < 4; ++t) {
            u16x4 pb;
#pragma unroll
            for (int r = 0; r < 4; ++r) {
                float pv = fast_exp2(lt[t][r] - m2);
                rs += pv;
                pb[r] = f2bf(pv);
            }
            *(u16x4*)&pw[c * 72 + (((16 * t + 4 * g) ^ xr))] = pb;
        }
        rs += __shfl_xor(rs, 16);
        rs += __shfl_xor(rs, 32);
        ln = ln * al + rs;
#pragma unroll
        for (int t2 = 0; t2 < 8; ++t2)
#pragma unroll
            for (int r = 0; r < 4; ++r) oacc[t2][r] *= al;

        // ---- O^T += V^T P^T : A = V^T frags from global, B = P^T from LDS ----
        {
            const u32x4* vp = (const u32x4*)vt_g + ((b * 128 + c) * 256 + (k0 >> 3) + g);
#pragma unroll
            for (int k2 = 0; k2 < 2; ++k2) {
                s16x8 bP = *(const s16x8*)&pw[c * 72 + ((32 * k2 + 8 * g) ^ xr)];
#pragma unroll
                for (int t2 = 0; t2 < 8; ++t2) {
                    s16x8 vA = __builtin_bit_cast(s16x8, vp[t2 * (16 * 256) + 4 * k2]);
                    oacc[t2] = __builtin_amdgcn_mfma_f32_16x16x32_bf16(vA, bP, oacc[t2], 0, 0, 0);
                }
            }
        }
    }

    // ---- write bf16 unnormalized partials + stats ----
    {
        const size_t obase = ((size_t)ks * 16384 + qrow) * 128;
#pragma unroll
        for (int t2 = 0; t2 < 8; ++t2) {
            u16x4 ob;
#pragma unroll
            for (int r = 0; r < 4; ++r) ob[r] = f2bf(oacc[t2][r]);
            *(u16x4*)&opart[obase + 16 * t2 + 4 * g] = ob;
        }
        if (g == 0) {
            mpart[ks * 16384 + qrow] = m2;
            lpart[ks * 16384 + qrow] = ln;
        }
    }
}

// ---------------- merge the four k-split quarters ----------------
__global__ void merge4(const unsigned short* __restrict__ opart,
                       const float* __restrict__ mpart,
                       const float* __restrict__ lpart,
                       float* __restrict__ out) {
    const int row = blockIdx.x;     // b*2048 + q
    const int d   = threadIdx.x;    // 0..127
    float m[KSPLIT];
    float M = -INFINITY;
#pragma unroll
    for (int s = 0; s < KSPLIT; ++s) { m[s] = mpart[s * 16384 + row]; M = fmaxf(M, m[s]); }
    float den = 0.f, acc = 0.f;
#pragma unroll
    for (int s = 0; s < KSPLIT; ++s) {
        const float a = fast_exp2(m[s] - M);
        den += a * lpart[s * 16384 + row];
        acc += a * bf2f(opart[((size_t)s * 16384 + row) * 128 + d]);
    }
    out[(size_t)row * 128 + d] = acc / den;
}

extern "C" void kernel_launch(void* const* d_in, const int* in_sizes, int n_in,
                              void* d_out, int out_size, void* d_ws, size_t ws_size,
                              hipStream_t stream) {
    const float* q  = (const float*)d_in[0];
    const float* k  = (const float*)d_in[1];
    const float* v  = (const float*)d_in[2];
    const float* sc = (const float*)d_in[3];
    float* out = (float*)d_out;

    char* ws = (char*)d_ws;
    const size_t MB = 1024 * 1024;
    unsigned short* qh = (unsigned short*)(ws);
    unsigned short* ql = (unsigned short*)(ws + 4 * MB);
    unsigned short* kh = (unsigned short*)(ws + 8 * MB);
    unsigned short* kl = (unsigned short*)(ws + 12 * MB);
    unsigned short* vt = (unsigned short*)(ws + 16 * MB);
    unsigned short* opart = (unsigned short*)(ws + 20 * MB);          // [4][16384][128] bf16
    float* mpart = (float*)(ws + 36 * MB);                            // [4][16384]
    float* lpart = (float*)(ws + 36 * MB + 256 * 1024);               // [4][16384]

    conv_split2<<<4096, 256, 0, stream>>>(q, k, qh, ql, kh, kl);
    transpose_v<<<1024, 256, 0, stream>>>(v, vt);
    flash_fwd<<<1024, 256, 0, stream>>>(qh, ql, kh, kl, vt, sc, opart, mpart, lpart);
    merge4<<<16384, 128, 0, stream>>>(opart, mpart, lpart, out);
}

// Round 3
// 299.749 us; speedup vs baseline: 1.3127x; 1.3127x over previous
//
#include <hip/hip_runtime.h>
#include <hip/hip_bf16.h>

// B=8, LQ=LK=2048, D=128, fp32 in/out: softmax(qk*scale) @ V.
// Flash attention, S^T/O^T orientation, 32x32x16 MFMA, kk-sliced waves:
//   block = 256 thr (4 waves), q-tile 32 shared, each wave owns a 32-key
//   slice of a 128-key chunk. K_hi staged in LDS (double-buffered async DMA,
//   source-address swizzle for bank-floor ds_read_b128); K_lo / V^T / scale
//   direct global->VGPR with long-range prefetch. bf16x3 QK for ~fp32 logits.
// Grid 512 = 8 batches x 64 q-tiles, 2 blocks/CU, no k-split, no merge.

typedef float          f32x4  __attribute__((ext_vector_type(4)));
typedef float          f32x16 __attribute__((ext_vector_type(16)));
typedef short          s16x8  __attribute__((ext_vector_type(8)));
typedef unsigned int   u32x4  __attribute__((ext_vector_type(4)));
typedef unsigned short u16x4  __attribute__((ext_vector_type(4)));

typedef const __attribute__((address_space(1))) unsigned int* gas_ptr;
typedef __attribute__((address_space(3))) unsigned int*       las_ptr;

#define LOG2E 1.4426950408889634f

__device__ __forceinline__ float fast_exp2(float x) {
#if __has_builtin(__builtin_amdgcn_exp2f)
    return __builtin_amdgcn_exp2f(x);
#else
    return exp2f(x);
#endif
}
__device__ __forceinline__ unsigned short f2bf(float x) {
    return __builtin_bit_cast(unsigned short, __float2bfloat16(x));
}
__device__ __forceinline__ float bf2f(unsigned short u) {
    return __bfloat162float(__builtin_bit_cast(__hip_bfloat16, u));
}

// ---------------- fp32 -> bf16 hi/lo split, Q and K fused ----------------
__global__ void conv_split2(const float* __restrict__ q, const float* __restrict__ k,
                            unsigned short* __restrict__ qh, unsigned short* __restrict__ ql,
                            unsigned short* __restrict__ kh, unsigned short* __restrict__ kl) {
    const int bid  = blockIdx.x;
    const int half = bid >> 11;                        // 0: q, 1: k
    const int i    = (bid & 2047) * 256 + threadIdx.x; // float4 idx
    const float* src = half ? k : q;
    unsigned short* hi = half ? kh : qh;
    unsigned short* lo = half ? kl : ql;
    const float4 v = ((const float4*)src)[i];
    float f[4] = {v.x, v.y, v.z, v.w};
    u16x4 h, l;
#pragma unroll
    for (int j = 0; j < 4; ++j) {
        unsigned short hb = f2bf(f[j]);
        h[j] = hb;
        l[j] = f2bf(f[j] - bf2f(hb));
    }
    ((u16x4*)hi)[i] = h;
    ((u16x4*)lo)[i] = l;
}

// -------- V [b][k][d] fp32 -> V^T [b][d][2048] bf16 --------
__global__ void transpose_v(const float* __restrict__ v,
                            unsigned short* __restrict__ vt) {
    __shared__ unsigned short tile[64 * 36];
    const int b    = blockIdx.x & 7;
    const int rest = blockIdx.x >> 3;
    const int k0   = (rest & 31) * 64;
    const int d0   = (rest >> 5) * 32;
    const int tid  = threadIdx.x;
#pragma unroll
    for (int it = 0; it < 2; ++it) {
        int idx = it * 256 + tid;
        int kk  = idx >> 3;
        int d4  = idx & 7;
        float4 val = ((const float4*)v)[((b * 2048 + k0 + kk) * 128 + d0 + d4 * 4) >> 2];
        u16x4 t4;
        t4[0] = f2bf(val.x); t4[1] = f2bf(val.y);
        t4[2] = f2bf(val.z); t4[3] = f2bf(val.w);
        *(u16x4*)&tile[kk * 36 + d4 * 4] = t4;
    }
    __syncthreads();
    {
        int d  = tid >> 3;
        int k8 = tid & 7;
        u16x4 a, cgrp;
#pragma unroll
        for (int j = 0; j < 4; ++j) a[j]    = tile[(k8 * 8 + j) * 36 + d];
#pragma unroll
        for (int j = 0; j < 4; ++j) cgrp[j] = tile[(k8 * 8 + 4 + j) * 36 + d];
        unsigned short* outp = vt + (b * 128 + d0 + d) * 2048 + k0 + k8 * 8;
        *(u16x4*)outp       = a;
        *(u16x4*)(outp + 4) = cgrp;
    }
}

// ---------------- flash attention main kernel ----------------
#define NKC 16          // 16 chunks x 128 keys
// LDS map (bytes):
//   khbuf : [2][32768]      0 .. 65536   (aliased by OEX at epilogue)
//   OEX   : [4][32][132] f32  0 .. 67584 (epilogue only)
//   pbuf  : [4][2560]      67584 .. 77824  (per-wave P^T, rows 32 x 80B)
//   mstat : [2][128] f32   77824 .. 78848
//   lstat : [128] f32      78848 .. 79360
#define LDS_TOTAL 79360
#define PBUF_OFF  67584
#define MSTAT_OFF 77824
#define LSTAT_OFF 78848

__global__ __launch_bounds__(256, 2)
void flash_fwd(const unsigned short* __restrict__ qh_g,
               const unsigned short* __restrict__ ql_g,
               const unsigned short* __restrict__ kh_g,
               const unsigned short* __restrict__ kl_g,
               const unsigned short* __restrict__ vt_g,
               const float* __restrict__ scale_g,
               float* __restrict__ out) {
    __shared__ unsigned char smem[LDS_TOTAL];
    unsigned char* khbuf = smem;
    float* mstat = (float*)(smem + MSTAT_OFF);
    float* lstat = (float*)(smem + LSTAT_OFF);
    float* oex   = (float*)smem;

    const int tid  = threadIdx.x;
    const int wave = tid >> 6;
    const int lane = tid & 63;
    const int qi   = lane & 31;
    const int g2   = lane >> 5;

    const int bid = blockIdx.x;
    const int b   = bid & 7;            // batch <-> XCD affinity
    const int qt  = bid >> 3;           // 0..63
    const int q0  = qt * 32;
    const int qrow = b * 2048 + q0 + qi;

    unsigned short* pw = (unsigned short*)(smem + PBUF_OFF + wave * 2560);

    // ---- Q B-fragments (resident): B[k=d][n=q], 8 ksteps, hi+lo ----
    s16x8 qhB[8], qlB[8];
#pragma unroll
    for (int s = 0; s < 8; ++s) {
        int idx = qrow * 16 + s * 2 + g2;
        qhB[s] = __builtin_bit_cast(s16x8, ((const u32x4*)qh_g)[idx]);
        qlB[s] = __builtin_bit_cast(s16x8, ((const u32x4*)ql_g)[idx]);
    }

    f32x16 oacc[4];
#pragma unroll
    for (int t = 0; t < 4; ++t)
#pragma unroll
        for (int r = 0; r < 16; ++r) oacc[t][r] = 0.f;
    float m_run = -INFINITY, l_run = 0.f;

    // ---- DMA helper constants ----
    const int krow_base = b * 2048;     // kh_g row base

    // prologue: DMA chunk 0 into buf0, load scale for kc=0
    {
#pragma unroll
        for (int j = 0; j < 8; ++j) {
            int o  = wave * 8192 + j * 1024 + lane * 16;   // byte off in buf
            int r  = o >> 8;
            int cp = (o >> 4) & 15;
            int cn = cp ^ (r & 7);
            const unsigned short* src = kh_g + ((krow_base + r) * 16 + cn) * 8;
            __builtin_amdgcn_global_load_lds((gas_ptr)(const void*)src,
                (las_ptr)(void*)(khbuf + wave * 8192 + j * 1024), 16, 0, 0);
        }
    }
    f32x4 scf[4];
    {
        const int sidx = qrow * 512 + wave * 8 + g2;
#pragma unroll
        for (int rg = 0; rg < 4; ++rg)
            scf[rg] = ((const f32x4*)scale_g)[sidx + rg * 2];
    }
    __syncthreads();

    for (int kc = 0; kc < NKC; ++kc) {
        const int k0  = kc * 128;
        const int cur = kc & 1;
        unsigned char* bufc = khbuf + cur * 32768;

        // ---- issue DMA for kc+1 into the other buffer ----
        if (kc + 1 < NKC) {
            unsigned char* bufn = khbuf + (cur ^ 1) * 32768;
#pragma unroll
            for (int j = 0; j < 8; ++j) {
                int o  = wave * 8192 + j * 1024 + lane * 16;
                int r  = o >> 8;
                int cp = (o >> 4) & 15;
                int cn = cp ^ (r & 7);
                const unsigned short* src = kh_g + ((krow_base + k0 + 128 + r) * 16 + cn) * 8;
                __builtin_amdgcn_global_load_lds((gas_ptr)(const void*)src,
                    (las_ptr)(void*)(bufn + wave * 8192 + j * 1024), 16, 0, 0);
            }
        }

        // ---- prefetch K_lo + V^T fragments (global, L2-resident) ----
        u32x4 klr[8], vr[8];
        {
            const int krow = krow_base + k0 + wave * 32 + qi;
#pragma unroll
            for (int s = 0; s < 8; ++s)
                klr[s] = ((const u32x4*)kl_g)[krow * 16 + s * 2 + g2];
            const int vbase = (b * 128 + qi) * 256 + ((k0 + wave * 32) >> 3) + g2;
#pragma unroll
            for (int t = 0; t < 4; ++t)
#pragma unroll
                for (int s2 = 0; s2 < 2; ++s2)
                    vr[t * 2 + s2] = ((const u32x4*)vt_g)[vbase + t * 32 * 256 + s2 * 2];
        }

        // ---- prefetch scale for kc+1 (HBM stream, one kc ahead) ----
        f32x4 scn[4];
        if (kc + 1 < NKC) {
            const int sidx = qrow * 512 + ((k0 + 128) >> 2) + wave * 8 + g2;
#pragma unroll
            for (int rg = 0; rg < 4; ++rg)
                scn[rg] = ((const f32x4*)scale_g)[sidx + rg * 2];
        }

        // ---- S^T = K Q^T over this wave's 32-key slice (bf16x3) ----
        f32x16 S;
#pragma unroll
        for (int r = 0; r < 16; ++r) S[r] = 0.f;
        s16x8 khf[8];
        {
            const int r  = wave * 32 + qi;          // LDS row 0..127
            const int rx = r & 7;
#pragma unroll
            for (int s = 0; s < 8; ++s) {
                int cp = (s * 2 + g2) ^ rx;
                khf[s] = *(const s16x8*)(bufc + r * 256 + cp * 16);
                S = __builtin_amdgcn_mfma_f32_32x32x16_bf16(khf[s], qhB[s], S, 0, 0, 0);
            }
#pragma unroll
            for (int s = 0; s < 8; ++s)
                S = __builtin_amdgcn_mfma_f32_32x32x16_bf16(
                        __builtin_bit_cast(s16x8, klr[s]), qhB[s], S, 0, 0, 0);
#pragma unroll
            for (int s = 0; s < 8; ++s)
                S = __builtin_amdgcn_mfma_f32_32x32x16_bf16(khf[s], qlB[s], S, 0, 0, 0);
        }

        // ---- logits, slice max, cross-wave max exchange ----
        float lt[16];
        float mx = -INFINITY;
#pragma unroll
        for (int r = 0; r < 16; ++r) {
            lt[r] = S[r] * (scf[r >> 2][r & 3] * LOG2E);
            mx = fmaxf(mx, lt[r]);
        }
        mx = fmaxf(mx, __shfl_xor(mx, 32));
        const int par = (kc & 1) * 128;
        if (g2 == 0) mstat[par + wave * 32 + qi] = mx;
        __syncthreads();   // stats fence + DMA(kc+1) vmcnt fence + buf reuse fence

        float m_new = m_run;
#pragma unroll
        for (int w = 0; w < 4; ++w)
            m_new = fmaxf(m_new, mstat[par + w * 32 + qi]);
        const float al = fast_exp2(m_run - m_new);
        m_run = m_new;
#pragma unroll
        for (int t = 0; t < 4; ++t)
#pragma unroll
            for (int r = 0; r < 16; ++r) oacc[t][r] *= al;

        // ---- P = exp2(lt - m), write P^T rows to per-wave LDS ----
        float rs = 0.f;
#pragma unroll
        for (int p = 0; p < 8; ++p) {
            float e0 = fast_exp2(lt[2 * p]     - m_new);
            float e1 = fast_exp2(lt[2 * p + 1] - m_new);
            rs += e0 + e1;
            unsigned int pk = (unsigned int)f2bf(e0) | ((unsigned int)f2bf(e1) << 16);
            int kk0 = ((2 * p) & 3) + 8 * (p >> 1) + 4 * g2;
            *(unsigned int*)&pw[qi * 40 + kk0] = pk;
        }
        rs += __shfl_xor(rs, 32);
        l_run = l_run * al + rs;

        // ---- O^T += V^T P^T over this wave's slice ----
        s16x8 bP[2];
#pragma unroll
        for (int s2 = 0; s2 < 2; ++s2)
            bP[s2] = *(const s16x8*)&pw[qi * 40 + s2 * 16 + g2 * 8];
#pragma unroll
        for (int t = 0; t < 4; ++t)
#pragma unroll
            for (int s2 = 0; s2 < 2; ++s2)
                oacc[t] = __builtin_amdgcn_mfma_f32_32x32x16_bf16(
                            __builtin_bit_cast(s16x8, vr[t * 2 + s2]), bP[s2], oacc[t], 0, 0, 0);

        if (kc + 1 < NKC) {
#pragma unroll
            for (int rg = 0; rg < 4; ++rg) scf[rg] = scn[rg];
        }
    }

    // ---- epilogue: cross-wave O reduction + normalize + store ----
    if (g2 == 0) lstat[wave * 32 + qi] = l_run;
#pragma unroll
    for (int t = 0; t < 4; ++t)
#pragma unroll
        for (int rg = 0; rg < 4; ++rg) {
            f32x4 v4;
#pragma unroll
            for (int j = 0; j < 4; ++j) v4[j] = oacc[t][rg * 4 + j];
            *(f32x4*)&oex[(wave * 32 + qi) * 132 + t * 32 + rg * 8 + g2 * 4] = v4;
        }
    __syncthreads();
    {
        const int q    = tid >> 3;
        const int dblk = tid & 7;
        const float linv = 1.f / (lstat[q] + lstat[32 + q] + lstat[64 + q] + lstat[96 + q]);
#pragma unroll
        for (int j = 0; j < 4; ++j) {
            const int d = dblk * 16 + j * 4;
            f32x4 acc = *(const f32x4*)&oex[q * 132 + d];
#pragma unroll
            for (int w = 1; w < 4; ++w) {
                f32x4 p = *(const f32x4*)&oex[(w * 32 + q) * 132 + d];
                acc[0] += p[0]; acc[1] += p[1]; acc[2] += p[2]; acc[3] += p[3];
            }
            acc[0] *= linv; acc[1] *= linv; acc[2] *= linv; acc[3] *= linv;
            *(f32x4*)&out[(size_t)(b * 2048 + q0 + q) * 128 + d] = acc;
        }
    }
}

extern "C" void kernel_launch(void* const* d_in, const int* in_sizes, int n_in,
                              void* d_out, int out_size, void* d_ws, size_t ws_size,
                              hipStream_t stream) {
    const float* q  = (const float*)d_in[0];
    const float* k  = (const float*)d_in[1];
    const float* v  = (const float*)d_in[2];
    const float* sc = (const float*)d_in[3];
    float* out = (float*)d_out;

    char* ws = (char*)d_ws;
    const size_t MB = 1024 * 1024;
    unsigned short* qh = (unsigned short*)(ws);
    unsigned short* ql = (unsigned short*)(ws + 4 * MB);
    unsigned short* kh = (unsigned short*)(ws + 8 * MB);
    unsigned short* kl = (unsigned short*)(ws + 12 * MB);
    unsigned short* vt = (unsigned short*)(ws + 16 * MB);

    conv_split2<<<4096, 256, 0, stream>>>(q, k, qh, ql, kh, kl);
    transpose_v<<<1024, 256, 0, stream>>>(v, vt);
    flash_fwd<<<512, 256, 0, stream>>>(qh, ql, kh, kl, vt, sc, out);
}

// Round 4
// 296.668 us; speedup vs baseline: 1.3263x; 1.0104x over previous
//
#include <hip/hip_runtime.h>

// B=8, LQ=LK=2048, D=128, fp32 in/out: softmax(qk*scale) @ V.
// Flash attention, S^T/O^T orientation, 32x32x16 f16 MFMA.
// Key ideas this round:
//  - fragment-major pre-layout of Q/K/V -> every flash global load is a
//    contiguous 1 KB wave load (no 32-row gathers)
//  - fp16x2 split QK (q=qh+ql fp16, k fp16) for accurate logits
//  - single-wave blocks, NO barriers; scale staged VGPR->LDS per wave
//  - P C->B layout fixup via lane^32 shuffle (no LDS round trip)

typedef float          f32x4  __attribute__((ext_vector_type(4)));
typedef float          f32x16 __attribute__((ext_vector_type(16)));
typedef _Float16       h16x8  __attribute__((ext_vector_type(8)));
typedef unsigned int   u32x4  __attribute__((ext_vector_type(4)));
typedef unsigned short u16x8  __attribute__((ext_vector_type(8)));

#define LOG2E 1.4426950408889634f

__device__ __forceinline__ float fast_exp2(float x) {
#if __has_builtin(__builtin_amdgcn_exp2f)
    return __builtin_amdgcn_exp2f(x);
#else
    return exp2f(x);
#endif
}

// ---------------- fused prep: Q/K/V -> fragment-major fp16 ----------------
// qhF/qlF/khF: frag row fr = ((b*64 + tile)*8 + s), 64 lanes x 8 fp16:
//   element j = X[b][tile*32 + (lane&31)][s*16 + (lane>>5)*8 + j]
// vF: frag row fr = ((b*64 + kc)*8 + td*2+s2), element j =
//   V[b][kc*32 + s2*16 + (lane>>5)*8 + j][td*32 + (lane&31)]
__global__ __launch_bounds__(256)
void prep_all(const float* __restrict__ q, const float* __restrict__ k,
              const float* __restrict__ v,
              unsigned short* __restrict__ qhF, unsigned short* __restrict__ qlF,
              unsigned short* __restrict__ khF, unsigned short* __restrict__ vF) {
    const int bid = blockIdx.x;
    if (bid < 2048) {                       // Q (with lo) and K (hi only)
        const bool isQ = bid < 1024;
        const int t    = (isQ ? bid : bid - 1024) * 256 + threadIdx.x; // 0..262143
        const int lane = t & 63;
        const int fr   = t >> 6;            // ((b*64+tile)*8+s)
        const int s    = fr & 7;
        const int tile = (fr >> 3) & 63;
        const int b    = fr >> 9;
        const int row  = b * 2048 + tile * 32 + (lane & 31);
        const int col  = s * 16 + (lane >> 5) * 8;
        const float* src = (isQ ? q : k) + row * 128 + col;
        float f[8];
        *(f32x4*)&f[0] = *(const f32x4*)src;
        *(f32x4*)&f[4] = *(const f32x4*)(src + 4);
        u16x8 hi, lo;
#pragma unroll
        for (int j = 0; j < 8; ++j) {
            _Float16 h = (_Float16)f[j];
            hi[j] = __builtin_bit_cast(unsigned short, h);
            _Float16 l = (_Float16)(f[j] - (float)h);
            lo[j] = __builtin_bit_cast(unsigned short, l);
        }
        if (isQ) {
            *(u16x8*)(qhF + (size_t)t * 8) = hi;
            *(u16x8*)(qlF + (size_t)t * 8) = lo;
        } else {
            *(u16x8*)(khF + (size_t)t * 8) = hi;
        }
    } else {                                // V: one block per (b, kc)
        __shared__ unsigned short tile[32 * 132];  // [k 32][d 128 +4]
        const int id = bid - 2048;          // 0..511
        const int b  = id >> 6;
        const int kc = id & 63;
        const int tid = threadIdx.x;
#pragma unroll
        for (int it = 0; it < 4; ++it) {
            int idx = it * 256 + tid;       // float4 idx 0..1023
            int kk  = idx >> 5;             // 0..31
            int c4  = idx & 31;
            f32x4 val = *(const f32x4*)(v + ((b * 2048 + kc * 32 + kk) * 128 + c4 * 4));
#pragma unroll
            for (int j = 0; j < 4; ++j)
                tile[kk * 132 + c4 * 4 + j] =
                    __builtin_bit_cast(unsigned short, (_Float16)val[j]);
        }
        __syncthreads();
#pragma unroll
        for (int e = 0; e < 2; ++e) {
            int fi   = e * 256 + tid;       // 0..511
            int lane = fi & 63;
            int fr2  = fi >> 6;             // td*2+s2
            int td   = fr2 >> 1;
            int s2   = fr2 & 1;
            u16x8 o;
#pragma unroll
            for (int j = 0; j < 8; ++j)
                o[j] = tile[(s2 * 16 + (lane >> 5) * 8 + j) * 132 + td * 32 + (lane & 31)];
            *(u16x8*)(vF + ((size_t)((b * 64 + kc) * 8 + fr2) * 64 + lane) * 8) = o;
        }
    }
}

// ---------------- flash attention main kernel ----------------
__global__ __launch_bounds__(64)
void flash_fwd(const unsigned short* __restrict__ qhF,
               const unsigned short* __restrict__ qlF,
               const unsigned short* __restrict__ khF,
               const unsigned short* __restrict__ vF,
               const float* __restrict__ scale_g,
               float* __restrict__ out) {
    __shared__ float scbuf[2][32 * 36];     // scale tile, row stride 144 B

    const int lane = threadIdx.x;
    const int q31  = lane & 31;
    const int h    = lane >> 5;

    const int bid = blockIdx.x;
    const int b   = bid & 7;                // batch <-> XCD affinity
    const int qt  = bid >> 3;               // 0..63

    // ---- resident Q fragments (coalesced 1 KB loads) ----
    h16x8 qh[8], ql[8];
    {
        const u32x4* qp = (const u32x4*)qhF + ((size_t)(b * 64 + qt) * 8) * 64 + lane;
        const u32x4* lp = (const u32x4*)qlF + ((size_t)(b * 64 + qt) * 8) * 64 + lane;
#pragma unroll
        for (int s = 0; s < 8; ++s) {
            qh[s] = __builtin_bit_cast(h16x8, qp[s * 64]);
            ql[s] = __builtin_bit_cast(h16x8, lp[s * 64]);
        }
    }

    const u32x4* khp = (const u32x4*)khF + ((size_t)(b * 64) * 8) * 64 + lane;
    const u32x4* vp  = (const u32x4*)vF  + ((size_t)(b * 64) * 8) * 64 + lane;

    // scale global row bases for the VGPR staging loads (lane j*8+(lane>>3) row)
    int scrow[4];
#pragma unroll
    for (int j = 0; j < 4; ++j)
        scrow[j] = (b * 2048 + qt * 32 + j * 8 + (lane >> 3)) * 2048 + (lane & 7) * 4;

    f32x16 oacc[4];
#pragma unroll
    for (int t = 0; t < 4; ++t)
#pragma unroll
        for (int r = 0; r < 16; ++r) oacc[t][r] = 0.f;
    float m_run = -INFINITY, l_run = 0.f;

    h16x8 khr[2][8], vr[2][8];
    f32x4 scv[2][4];

    // ---- prologue: chunk 0 frags, scale chunks 0 and 1; stage scale(0) ----
#pragma unroll
    for (int s = 0; s < 8; ++s) khr[0][s] = __builtin_bit_cast(h16x8, khp[s * 64]);
#pragma unroll
    for (int f = 0; f < 8; ++f) vr[0][f]  = __builtin_bit_cast(h16x8, vp[f * 64]);
#pragma unroll
    for (int j = 0; j < 4; ++j) scv[0][j] = *(const f32x4*)(scale_g + scrow[j]);
#pragma unroll
    for (int j = 0; j < 4; ++j) scv[1][j] = *(const f32x4*)(scale_g + scrow[j] + 32);
#pragma unroll
    for (int j = 0; j < 4; ++j)
        *(f32x4*)&scbuf[0][(j * 8 + (lane >> 3)) * 36 + (lane & 7) * 4] = scv[0][j];

    for (int kc2 = 0; kc2 < 32; ++kc2) {
#pragma unroll
        for (int u = 0; u < 2; ++u) {
            const int kc  = kc2 * 2 + u;
            const int cur = u, nxt = u ^ 1;
            const int kn  = (kc + 1) & 63;
            const int ks2 = (kc + 2) & 63;

            // 1) prefetch next chunk's K/V fragments (coalesced)
#pragma unroll
            for (int s = 0; s < 8; ++s)
                khr[nxt][s] = __builtin_bit_cast(h16x8, khp[(kn * 8 + s) * 64]);
#pragma unroll
            for (int f = 0; f < 8; ++f)
                vr[nxt][f]  = __builtin_bit_cast(h16x8, vp[(kn * 8 + f) * 64]);

            // 2) stage scale(kc+1) VGPR -> LDS  (buffer parity nxt)
#pragma unroll
            for (int j = 0; j < 4; ++j)
                *(f32x4*)&scbuf[nxt][(j * 8 + (lane >> 3)) * 36 + (lane & 7) * 4] = scv[nxt][j];

            // 3) reload scv[cur] <- scale(kc+2)  (coalesced 8-row loads)
#pragma unroll
            for (int j = 0; j < 4; ++j)
                scv[cur][j] = *(const f32x4*)(scale_g + scrow[j] + ks2 * 32);

            // 4) S^T = K Q^T  (fp16x2: kh*qh + kh*ql)
            f32x16 S;
#pragma unroll
            for (int r = 0; r < 16; ++r) S[r] = 0.f;
#pragma unroll
            for (int s = 0; s < 8; ++s) {
                S = __builtin_amdgcn_mfma_f32_32x32x16_f16(khr[cur][s], qh[s], S, 0, 0, 0);
                S = __builtin_amdgcn_mfma_f32_32x32x16_f16(khr[cur][s], ql[s], S, 0, 0, 0);
            }

            // 5) gather scale(kc) from LDS: lane (q,h) reads seg 2G+h of row q
            f32x4 scf[4];
#pragma unroll
            for (int G = 0; G < 4; ++G)
                scf[G] = *(const f32x4*)&scbuf[cur][q31 * 36 + (2 * G + h) * 4];

            // 6) online softmax (row q spans lane and lane^32)
            float lt[16];
            float mx = -INFINITY;
#pragma unroll
            for (int r = 0; r < 16; ++r) {
                lt[r] = S[r] * scf[r >> 2][r & 3];
                mx = fmaxf(mx, lt[r]);
            }
            mx = fmaxf(mx, __shfl_xor(mx, 32));
            const float m_new = fmaxf(m_run, mx);
            const float al = fast_exp2((m_run - m_new) * LOG2E);
            m_run = m_new;
            float rs = 0.f;
            float p[16];
#pragma unroll
            for (int r = 0; r < 16; ++r) {
                p[r] = fast_exp2((lt[r] - m_new) * LOG2E);
                rs += p[r];
            }
            rs += __shfl_xor(rs, 32);
            l_run = l_run * al + rs;
#pragma unroll
            for (int t = 0; t < 4; ++t)
#pragma unroll
                for (int r = 0; r < 16; ++r) oacc[t][r] *= al;

            // 7) P C-layout -> B-frag via lane^32 exchange
            unsigned int pa[4], pb[4];
#pragma unroll
            for (int G = 0; G < 4; ++G) {
                pa[G] = __builtin_bit_cast(unsigned int,
                         __builtin_amdgcn_cvt_pkrtz(p[4 * G + 0], p[4 * G + 1]));
                pb[G] = __builtin_bit_cast(unsigned int,
                         __builtin_amdgcn_cvt_pkrtz(p[4 * G + 2], p[4 * G + 3]));
            }
            h16x8 B[2];
#pragma unroll
            for (int s2 = 0; s2 < 2; ++s2) {
                const int Gk = 2 * s2 + h;
                unsigned int sa = h ? pa[2 * s2] : pa[2 * s2 + 1];
                unsigned int sb = h ? pb[2 * s2] : pb[2 * s2 + 1];
                unsigned int xa = (unsigned int)__shfl_xor((int)sa, 32);
                unsigned int xb = (unsigned int)__shfl_xor((int)sb, 32);
                u32x4 w;
                w[0] = h ? xa : pa[Gk];
                w[1] = h ? xb : pb[Gk];
                w[2] = h ? pa[Gk] : xa;
                w[3] = h ? pb[Gk] : xb;
                B[s2] = __builtin_bit_cast(h16x8, w);
            }

            // 8) O^T += V^T P^T
#pragma unroll
            for (int t = 0; t < 4; ++t)
#pragma unroll
                for (int s2 = 0; s2 < 2; ++s2)
                    oacc[t] = __builtin_amdgcn_mfma_f32_32x32x16_f16(
                                vr[cur][t * 2 + s2], B[s2], oacc[t], 0, 0, 0);
        }
    }

    // ---- epilogue: normalize + store ----
    const float linv = 1.f / l_run;
    const size_t orow = (size_t)(b * 2048 + qt * 32 + q31) * 128;
#pragma unroll
    for (int t = 0; t < 4; ++t)
#pragma unroll
        for (int G = 0; G < 4; ++G) {
            f32x4 o4;
#pragma unroll
            for (int j = 0; j < 4; ++j) o4[j] = oacc[t][4 * G + j] * linv;
            *(f32x4*)(out + orow + t * 32 + G * 8 + 4 * h) = o4;
        }
}

extern "C" void kernel_launch(void* const* d_in, const int* in_sizes, int n_in,
                              void* d_out, int out_size, void* d_ws, size_t ws_size,
                              hipStream_t stream) {
    const float* q  = (const float*)d_in[0];
    const float* k  = (const float*)d_in[1];
    const float* v  = (const float*)d_in[2];
    const float* sc = (const float*)d_in[3];
    float* out = (float*)d_out;

    char* ws = (char*)d_ws;
    const size_t MB = 1024 * 1024;
    unsigned short* qhF = (unsigned short*)(ws);
    unsigned short* qlF = (unsigned short*)(ws + 4 * MB);
    unsigned short* khF = (unsigned short*)(ws + 8 * MB);
    unsigned short* vF  = (unsigned short*)(ws + 12 * MB);

    prep_all<<<2560, 256, 0, stream>>>(q, k, v, qhF, qlF, khF, vF);
    flash_fwd<<<512, 64, 0, stream>>>(qhF, qlF, khF, vF, sc, out);
}